// Round 10
// baseline (2352.307 us; speedup 1.0000x reference)
//
#include <hip/hip_runtime.h>
#include <hip/hip_bf16.h>
#include <stdint.h>

typedef unsigned short ushort_t;
typedef unsigned long long ull_t;
using bf16x8 = __attribute__((ext_vector_type(8))) short;
using f32x4  = __attribute__((ext_vector_type(4))) float;

#define SEQ    256
#define BATCH  64
#define INDIM  512
#define HDIM   1024
#define OUTDIM 256
#define MTOT   (SEQ*BATCH)   // 16384
#define BH     (BATCH*HDIM)
#define WPAD   1032          // padded row stride (ushorts) for LDS weights

__device__ __forceinline__ ushort_t f2bf(float f) {
  uint32_t u = __builtin_bit_cast(uint32_t, f);
  u += 0x7fffu + ((u >> 16) & 1u);
  return (ushort_t)(u >> 16);
}
__device__ __forceinline__ float bf2f(ushort_t b) {
  uint32_t u = ((uint32_t)b) << 16;
  return __builtin_bit_cast(float, u);
}
__device__ __forceinline__ f32x4 mfma16(bf16x8 a, bf16x8 b, f32x4 c) {
  return __builtin_amdgcn_mfma_f32_16x16x32_bf16(a, b, c, 0, 0, 0);
}
__device__ __forceinline__ void gload16(const void* g, void* l) {
  __builtin_amdgcn_global_load_lds(
      (const __attribute__((address_space(1))) unsigned int*)g,
      (__attribute__((address_space(3))) unsigned int*)l, 16, 0, 0);
}
__device__ __forceinline__ float tanhfast(float z) {
  float e = __expf(2.0f * z);
  return 1.0f - 2.0f / (e + 1.0f);
}
// L1-bypassing L2 read (flag poll fast path). waitcnt fused in asm (rule #18).
__device__ __forceinline__ int load_sc0_int(const int* p) {
  int v;
  asm volatile("global_load_dword %0, %1, off sc0\n\ts_waitcnt vmcnt(0)"
               : "=&v"(v) : "v"(p) : "memory");
  return v;
}
// L1-bypassing store straight to L2 (flag publish fast path).
__device__ __forceinline__ void store_sc0_int(int* p, int v) {
  asm volatile("global_store_dword %0, %1, off sc0" :: "v"(p), "v"(v) : "memory");
}

// ---------------- prep kernels ----------------
__global__ void k_convert(const float* __restrict__ src, ushort_t* __restrict__ dst, int n) {
  int i = blockIdx.x * blockDim.x + threadIdx.x;
  if (i < n) dst[i] = f2bf(src[i]);
}
__global__ void k_split(const float* __restrict__ src, ushort_t* __restrict__ hi,
                        ushort_t* __restrict__ lo, int n) {
  int i = blockIdx.x * blockDim.x + threadIdx.x;
  if (i < n) {
    float v = src[i];
    ushort_t h = f2bf(v);
    hi[i] = h;
    lo[i] = f2bf(v - bf2f(h));
  }
}
__global__ void k_split_wc(const float* __restrict__ Wc,
                           ushort_t* __restrict__ WiH, ushort_t* __restrict__ WiL,
                           ushort_t* __restrict__ WhH, ushort_t* __restrict__ WhL) {
  int i = blockIdx.x * blockDim.x + threadIdx.x;
  if (i < HDIM * HDIM) {
    int row = i >> 10, k = i & 1023;
    float vi = Wc[(size_t)row * (2 * HDIM) + k];
    float vh = Wc[(size_t)row * (2 * HDIM) + HDIM + k];
    ushort_t ih = f2bf(vi);
    WiH[i] = ih; WiL[i] = f2bf(vi - bf2f(ih));
    ushort_t hh = f2bf(vh);
    WhH[i] = hh; WhL[i] = f2bf(vh - bf2f(hh));
  }
}

// ---------------- generic NT GEMM (validated r1-r9) ----------------
template<int SPLITB, int RELU, int OUTBF>
__global__ __launch_bounds__(256) void gemm_nt(
    const ushort_t* __restrict__ A, const ushort_t* __restrict__ Bhi,
    const ushort_t* __restrict__ Blo, const float* __restrict__ bias,
    float* __restrict__ Cf, ushort_t* __restrict__ Cb,
    int M, int N, int K)
{
  __shared__ ushort_t As[128 * 32];
  __shared__ ushort_t Bh[128 * 32];
  __shared__ ushort_t Bl[128 * 32];
  const int tid = threadIdx.x;
  const int w = tid >> 6, l = tid & 63;
  const int m0 = blockIdx.x * 128, n0 = blockIdx.y * 128;
  const int wr = w >> 1, wc = w & 1;
  const int lr = l & 15, lk = l >> 4;

  f32x4 acc[4][4] = {};
  const int nK = K >> 5;
  const size_t rowB = (size_t)K * 2;

  for (int kk = 0; kk < nK; ++kk) {
    const size_t kbyte = (size_t)kk * 64;
#pragma unroll
    for (int j = 0; j < 2; ++j) {
      int c = (w * 2 + j) * 64 + l;
      int row = c >> 2;
      int kb = (c & 3) * 16;
      gload16((const char*)A + (size_t)(m0 + row) * rowB + kbyte + kb,
              (char*)As + (w * 2 + j) * 1024);
      gload16((const char*)Bhi + (size_t)(n0 + row) * rowB + kbyte + kb,
              (char*)Bh + (w * 2 + j) * 1024);
      if (SPLITB)
        gload16((const char*)Blo + (size_t)(n0 + row) * rowB + kbyte + kb,
                (char*)Bl + (w * 2 + j) * 1024);
    }
    __syncthreads();
    bf16x8 af[4], bhf[4], blf[4];
#pragma unroll
    for (int i = 0; i < 4; ++i) {
      af[i]  = *(const bf16x8*)&As[(wr * 64 + i * 16 + lr) * 32 + lk * 8];
      bhf[i] = *(const bf16x8*)&Bh[(wc * 64 + i * 16 + lr) * 32 + lk * 8];
      if (SPLITB)
        blf[i] = *(const bf16x8*)&Bl[(wc * 64 + i * 16 + lr) * 32 + lk * 8];
    }
#pragma unroll
    for (int i = 0; i < 4; ++i)
#pragma unroll
      for (int j2 = 0; j2 < 4; ++j2) {
        acc[i][j2] = mfma16(af[i], bhf[j2], acc[i][j2]);
        if (SPLITB) acc[i][j2] = mfma16(af[i], blf[j2], acc[i][j2]);
      }
    __syncthreads();
  }
#pragma unroll
  for (int j2 = 0; j2 < 4; ++j2) {
    int n = n0 + wc * 64 + j2 * 16 + lr;
    float bv = bias ? bias[n] : 0.0f;
#pragma unroll
    for (int i = 0; i < 4; ++i) {
#pragma unroll
      for (int r = 0; r < 4; ++r) {
        int m = m0 + wr * 64 + i * 16 + lk * 4 + r;
        float v = acc[i][j2][r] + bv;
        if (RELU) v = fmaxf(v, 0.0f);
        if (OUTBF) Cb[(size_t)m * N + n] = f2bf(v);
        else       Cf[(size_t)m * N + n] = v;
      }
    }
  }
}

// ---------------- persistent scan kernel: barrier-free wave pipelines --------
// 512 blocks x 512 threads (8 waves). Workers: XCDs 0-3 x 32 slots (claim via
// XCC_ID + atomic; over-provisioned grid -> hang-proof). Block (g,c): batch
// rows 16g..16g+15, cols 32c..32c+31.
// r10: ZERO __syncthreads in the loop (r5-r9: the block barrier + 8-way reduce
// convoyed every block to all 32 producers each step - the invariant 4.4us).
// 8 waves = 4 tiles (phase A/B x col-tile 0/1) x 2 K-halves (K=512 each).
// Each wave: poll -> load state -> 16..48 MFMA -> pairwise reduce (LDS seq
// flag, partner wave only) -> tanh -> 4 stores -> vmcnt ack -> own flag
// publish (64 flags/group, 64B apart, sc0 + MALL dual path).
// Only lo-waves poll globally (lane l -> flag l); hi-waves spin on LDS epoch.
// Weights: WhH+WhL in LDS (132KB, forces 1 block/CU); per-wave WhL(A)/WiH(B)
// K-half slice in 64 pinned VGPRs (r8-proven). WiL dropped (r8, absmax 0.070).
// Iter i: A: h0(i)   = h0(i-1) + a0*tanh(P0[i] + Wh*h0(i-1))         [i<SEQ]
//         B: h1(i-1) = h1(i-2) + a1*tanh(WiH*h0(i-1)+Wh*h1(i-2)+b_c) [i>=1]
__global__ __attribute__((amdgpu_waves_per_eu(2, 2))) __launch_bounds__(512)
void scan_kernel(
    const float* __restrict__ P0,
    const ushort_t* __restrict__ WiH, const ushort_t* __restrict__ WiL,
    const ushort_t* __restrict__ WhH, const ushort_t* __restrict__ WhL,
    const float* __restrict__ b_c, const float* __restrict__ taus,
    ushort_t* __restrict__ h0buf,   // SEQ x 64x1024 bf16 (archive)
    ushort_t* __restrict__ H1buf,   // SEQ x 64x1024 bf16 (archive = h1 state)
    float* __restrict__ outHidden, int* __restrict__ sync)
{
  __shared__ ushort_t WhHs[32 * WPAD];   // 66KB
  __shared__ ushort_t WhLs[32 * WPAD];   // 66KB  -> 132KB total, 1 block/CU
  __shared__ float slotf[4 * 64 * 4];    // pairwise-reduce partials, 4KB
  __shared__ int seqw[4];                // per-pair reduce sequence
  __shared__ int epw[4];                 // per-pair poll epoch (lo -> hi)
  __shared__ int meta[2];

  const int tid = threadIdx.x;
  const int w = tid >> 6, l = tid & 63;
  const int lr = l & 15, lk = l >> 4;

  int* cnt = sync;  // [8] per-XCD slot counters
  // flag arrays: 4 groups x 64 flags x 16-int spacing (64B apart)
  int* A_l2   = sync + 256;
  int* A_mall = sync + 256 + 4096;
  int* B_l2   = sync + 256 + 8192;
  int* B_mall = sync + 256 + 12288;

  // ---- placement discovery ----
  if (tid == 0) {
    int xcd;
    asm volatile("s_getreg_b32 %0, hwreg(HW_REG_XCC_ID)" : "=s"(xcd));
    int slot = 999;
    if (xcd < 4)
      slot = __hip_atomic_fetch_add(&cnt[xcd], 1, __ATOMIC_RELAXED,
                                    __HIP_MEMORY_SCOPE_AGENT);
    meta[0] = (xcd < 4) ? xcd : -1;
    meta[1] = slot;
  }
  if (tid < 4) { seqw[tid] = 0; epw[tid] = 0; }
  __syncthreads();
  const int g = meta[0];
  const int c = meta[1];
  if (g < 0 || c >= 32) return;   // surplus block: exit, frees the CU

  const int rowg = g * 16, colg = c * 32;
  const int pair = w & 3;          // logical tile
  const int ph = pair >> 1;        // 0 = layer0(A), 1 = layer1(B)
  const int ect = pair & 1;        // col-tile within block
  const int half = w >> 2;         // K-half: 0 = [0,512), 1 = [512,1024)
  const int tc = colg + ect * 16;  // tile col base (global)

  // ---- one-time: WhH + WhL slices -> LDS (reg-staged, padded rows) ----
  {
    const ushort_t* s1 = WhH + (size_t)colg * HDIM;
    const ushort_t* s2 = WhL + (size_t)colg * HDIM;
#pragma unroll
    for (int j = 0; j < 8; ++j) {
      int e = (j * 512 + tid) * 8;
      *(bf16x8*)&WhHs[(e >> 10) * WPAD + (e & 1023)] = *(const bf16x8*)&s1[e];
      *(bf16x8*)&WhLs[(e >> 10) * WPAD + (e & 1023)] = *(const bf16x8*)&s2[e];
    }
  }
  // ---- one-time: per-wave reg slice (16 frags = 64 VGPR, pinned per-iter) ----
  // A-waves: WhL K-half (lo path for h0 term comes from regs, hi from LDS)
  // B-waves: WiH K-half
  bf16x8 wreg[16];
  {
    const ushort_t* ws = (ph == 0) ? WhL : WiH;
#pragma unroll
    for (int kk = 0; kk < 16; ++kk)
      wreg[kk] = *(const bf16x8*)&ws[(size_t)(tc + lr) * HDIM + half * 512 + kk * 32 + lk * 8];
  }
  __syncthreads();   // LDS weights ready (one-time; loop itself is barrier-free)

  // flag pointers
  const int* Apl = &A_l2[(g * 64 + l) * 16];
  int*       Apm = &A_mall[(g * 64 + l) * 16];
  const int* Bpl = &B_l2[(g * 64 + l) * 16];
  int*       Bpm = &B_mall[(g * 64 + l) * 16];
  int* myl2 = (ph == 0) ? &A_l2[(g * 64 + c * 2 + ect) * 16] : &B_l2[(g * 64 + c * 2 + ect) * 16];
  int* myml = (ph == 0) ? &A_mall[(g * 64 + c * 2 + ect) * 16] : &B_mall[(g * 64 + c * 2 + ect) * 16];

  // epilogue state (lo waves): lane holds col tc+lr, rows rowg+lk*4..+3
  float hm[4] = {0, 0, 0, 0};
  float p0r[4] = {0, 0, 0, 0};
  const float alpha = 0.05f / (taus[ph] + 0.001f);
  const float bcn = b_c[tc + lr];
  if (half == 0 && ph == 0) {
#pragma unroll
    for (int j = 0; j < 4; ++j)
      p0r[j] = P0[((size_t)0 * BATCH + rowg + lk * 4 + j) * HDIM + tc + lr];
  }

  const int ldsrow = (ect * 16 + lr) * WPAD + half * 512;

  for (int i = 0; i <= SEQ; ++i) {
#pragma unroll
    for (int kk = 0; kk < 16; ++kk)
      asm volatile("" : "+v"(wreg[kk]));

    // ---- dependency wait ----
    if (i >= 1) {
      if (half == 0) {
        const int tA = i, tB = i - 1;
        bool okA = false, okB = (ph == 0) || (i < 2);
        int rr = 0;
        do {
          if (rr >= 2) __builtin_amdgcn_s_sleep(1);
          if (!okA) {
            int v = ((rr & 7) == 7)
              ? __hip_atomic_load(Apm, __ATOMIC_RELAXED, __HIP_MEMORY_SCOPE_AGENT)
              : load_sc0_int(Apl);
            okA = (__all(v >= tA) != 0);
          }
          if (!okB) {
            int v = ((rr & 7) == 7)
              ? __hip_atomic_load(Bpm, __ATOMIC_RELAXED, __HIP_MEMORY_SCOPE_AGENT)
              : load_sc0_int(Bpl);
            okB = (__all(v >= tB) != 0);
          }
          ++rr;
        } while (!(okA && okB));
        *(volatile int*)&epw[pair] = i;    // release hi partner
      } else {
        int ev;
        do { ev = *(volatile int*)&epw[pair]; } while (ev < i);
      }
    }

    // ---- compute partial (K-half) ----
    f32x4 acc = {};
    if (i >= 1) {
      const ushort_t* h0p = h0buf + (size_t)(i - 1) * BH +
                            (size_t)(rowg + lr) * HDIM + half * 512 + lk * 8;
      if (ph == 0) {
#pragma unroll
        for (int kk = 0; kk < 16; ++kk) {
          bf16x8 f  = *(const bf16x8*)&h0p[kk * 32];
          bf16x8 wh = *(const bf16x8*)&WhHs[ldsrow + kk * 32 + lk * 8];
          acc = mfma16(f, wh, acc);
          acc = mfma16(f, wreg[kk], acc);
        }
      } else if (i >= 2) {
        const ushort_t* h1p = H1buf + (size_t)(i - 2) * BH +
                              (size_t)(rowg + lr) * HDIM + half * 512 + lk * 8;
#pragma unroll
        for (int kk = 0; kk < 16; ++kk) {
          bf16x8 f   = *(const bf16x8*)&h0p[kk * 32];
          bf16x8 hh  = *(const bf16x8*)&h1p[kk * 32];
          bf16x8 whh = *(const bf16x8*)&WhHs[ldsrow + kk * 32 + lk * 8];
          bf16x8 whl = *(const bf16x8*)&WhLs[ldsrow + kk * 32 + lk * 8];
          acc = mfma16(f, wreg[kk], acc);
          acc = mfma16(hh, whh, acc);
          acc = mfma16(hh, whl, acc);
        }
      } else {
#pragma unroll
        for (int kk = 0; kk < 16; ++kk) {
          bf16x8 f = *(const bf16x8*)&h0p[kk * 32];
          acc = mfma16(f, wreg[kk], acc);
        }
      }
    }

    const bool active = (ph == 0) ? (i < SEQ) : (i >= 1);
    const bool red_on = active && (i >= 1);

    if (half == 1) {
      // partner: hand partial to lo wave
      if (red_on) {
        *(f32x4*)&slotf[(pair * 64 + l) * 4] = acc;
        asm volatile("s_waitcnt lgkmcnt(0)" ::: "memory");
        if (l == 0) *(volatile int*)&seqw[pair] = i + 1;
      }
    } else if (active) {
      if (red_on) {
        int sv;
        do { sv = *(volatile int*)&seqw[pair]; } while (sv <= i);
        acc += *(const f32x4*)&slotf[(pair * 64 + l) * 4];
      }
      // epilogue: lane col tc+lr, rows lk*4+j
      if (ph == 0) {
        ushort_t* dst = &h0buf[(size_t)i * BH + (size_t)(rowg + lk * 4) * HDIM + tc + lr];
#pragma unroll
        for (int j = 0; j < 4; ++j) {
          hm[j] += alpha * tanhfast(p0r[j] + acc[j]);
          dst[(size_t)j * HDIM] = f2bf(hm[j]);
        }
      } else {
        ushort_t* dst = &H1buf[(size_t)(i - 1) * BH + (size_t)(rowg + lk * 4) * HDIM + tc + lr];
#pragma unroll
        for (int j = 0; j < 4; ++j) {
          hm[j] += alpha * tanhfast(acc[j] + bcn);
          dst[(size_t)j * HDIM] = f2bf(hm[j]);
        }
      }
      asm volatile("s_waitcnt vmcnt(0)" ::: "memory");  // stores acked at L2
      if (l == 0) {
        const int fv = (ph == 0) ? (i + 1) : i;
        store_sc0_int(myl2, fv);
        __hip_atomic_store(myml, fv, __ATOMIC_RELAXED, __HIP_MEMORY_SCOPE_AGENT);
      }
      if (ph == 0 && i + 1 < SEQ) {    // prefetch next P0 tile
#pragma unroll
        for (int j = 0; j < 4; ++j)
          p0r[j] = P0[((size_t)(i + 1) * BATCH + rowg + lk * 4 + j) * HDIM + tc + lr];
      }
    }
  }

  // hidden_final [2][64][1024]
  if (half == 0) {
    float* dst = &outHidden[(size_t)ph * BH + (size_t)(rowg + lk * 4) * HDIM + tc + lr];
#pragma unroll
    for (int j = 0; j < 4; ++j) dst[(size_t)j * HDIM] = hm[j];
  }
}

// ---------------- host ----------------
extern "C" void kernel_launch(void* const* d_in, const int* in_sizes, int n_in,
                              void* d_out, int out_size, void* d_ws, size_t ws_size,
                              hipStream_t stream) {
  const float* x    = (const float*)d_in[0];
  const float* W_in = (const float*)d_in[1];
  const float* b_in = (const float*)d_in[2];
  const float* W_c  = (const float*)d_in[3];
  const float* b_c  = (const float*)d_in[4];
  const float* taus = (const float*)d_in[5];
  const float* W_o1 = (const float*)d_in[6];
  const float* b_o1 = (const float*)d_in[7];
  const float* W_o2 = (const float*)d_in[8];
  const float* b_o2 = (const float*)d_in[9];
  float* out = (float*)d_out;

  char* ws = (char*)d_ws;
  size_t off = 0;
  auto alloc = [&](size_t bytes) -> char* {
    char* p = ws + off;
    off += (bytes + 255) & ~(size_t)255;
    return p;
  };
  ushort_t* x_bf  = (ushort_t*)alloc((size_t)MTOT * INDIM * 2);     // 16 MB
  ushort_t* xp_b  = (ushort_t*)alloc((size_t)MTOT * HDIM * 2);      // 32 MB
  float*    P0    = (float*)   alloc((size_t)MTOT * HDIM * 4);      // 64 MB
  ushort_t* H1buf = (ushort_t*)alloc((size_t)MTOT * HDIM * 2);      // 32 MB
  ushort_t* h0buf = (ushort_t*)alloc((size_t)SEQ * BH * 2);         // 32 MB
  ushort_t* O1    = (ushort_t*)alloc((size_t)MTOT * (HDIM/2) * 2);  // 16 MB
  ushort_t* WiH   = (ushort_t*)alloc((size_t)HDIM * HDIM * 2);
  ushort_t* WiL   = (ushort_t*)alloc((size_t)HDIM * HDIM * 2);
  ushort_t* WhH   = (ushort_t*)alloc((size_t)HDIM * HDIM * 2);
  ushort_t* WhL   = (ushort_t*)alloc((size_t)HDIM * HDIM * 2);
  ushort_t* WinH  = (ushort_t*)alloc((size_t)HDIM * INDIM * 2);
  ushort_t* WinL  = (ushort_t*)alloc((size_t)HDIM * INDIM * 2);
  ushort_t* Wo1b  = (ushort_t*)alloc((size_t)(HDIM/2) * HDIM * 2);
  ushort_t* Wo2b  = (ushort_t*)alloc((size_t)OUTDIM * (HDIM/2) * 2);
  int*      sync  = (int*)     alloc(131072);
  if (off > ws_size) return;

  hipMemsetAsync(sync, 0, 131072, stream);

  k_convert<<<(MTOT * INDIM + 255) / 256, 256, 0, stream>>>(x, x_bf, MTOT * INDIM);
  k_split<<<(HDIM * INDIM + 255) / 256, 256, 0, stream>>>(W_in, WinH, WinL, HDIM * INDIM);
  k_split_wc<<<(HDIM * HDIM + 255) / 256, 256, 0, stream>>>(W_c, WiH, WiL, WhH, WhL);
  k_convert<<<((HDIM/2) * HDIM + 255) / 256, 256, 0, stream>>>(W_o1, Wo1b, (HDIM/2) * HDIM);
  k_convert<<<(OUTDIM * (HDIM/2) + 255) / 256, 256, 0, stream>>>(W_o2, Wo2b, OUTDIM * (HDIM/2));

  // xp = x @ W_in^T + b_in   -> bf16
  gemm_nt<1, 0, 1><<<dim3(MTOT / 128, HDIM / 128), 256, 0, stream>>>(
      x_bf, WinH, WinL, b_in, nullptr, xp_b, MTOT, HDIM, INDIM);
  // P0 = xp @ Wi^T + b_c     -> fp32
  gemm_nt<1, 0, 0><<<dim3(MTOT / 128, HDIM / 128), 256, 0, stream>>>(
      xp_b, WiH, WiL, b_c, P0, nullptr, MTOT, HDIM, HDIM);

  // sequential scan: 4 XCD-local groups x 32 worker blocks x 8 waves
  scan_kernel<<<512, 512, 0, stream>>>(P0, WiH, WiL, WhH, WhL, b_c, taus,
                                       h0buf, H1buf,
                                       out + (size_t)SEQ * BATCH * OUTDIM, sync);

  // O1 = relu(H1 @ W_o1^T + b_o1) -> bf16
  gemm_nt<0, 1, 1><<<dim3(MTOT / 128, (HDIM/2) / 128), 256, 0, stream>>>(
      H1buf, Wo1b, nullptr, b_o1, nullptr, O1, MTOT, HDIM / 2, HDIM);
  // out = O1 @ W_o2^T + b_o2 -> fp32
  gemm_nt<0, 0, 0><<<dim3(MTOT / 128, OUTDIM / 128), 256, 0, stream>>>(
      O1, Wo2b, nullptr, b_o2, out, nullptr, MTOT, OUTDIM, HDIM / 2);
}

// Round 11
// 1635.919 us; speedup vs baseline: 1.4379x; 1.4379x over previous
//
#include <hip/hip_runtime.h>
#include <hip/hip_bf16.h>
#include <stdint.h>

typedef unsigned short ushort_t;
typedef unsigned long long ull_t;
using bf16x8 = __attribute__((ext_vector_type(8))) short;
using f32x4  = __attribute__((ext_vector_type(4))) float;

#define SEQ    256
#define BATCH  64
#define INDIM  512
#define HDIM   1024
#define OUTDIM 256
#define MTOT   (SEQ*BATCH)   // 16384
#define BH     (BATCH*HDIM)
#define WPAD   1032          // padded row stride (ushorts) for LDS weights

__device__ __forceinline__ ushort_t f2bf(float f) {
  uint32_t u = __builtin_bit_cast(uint32_t, f);
  u += 0x7fffu + ((u >> 16) & 1u);
  return (ushort_t)(u >> 16);
}
__device__ __forceinline__ float bf2f(ushort_t b) {
  uint32_t u = ((uint32_t)b) << 16;
  return __builtin_bit_cast(float, u);
}
__device__ __forceinline__ f32x4 mfma16(bf16x8 a, bf16x8 b, f32x4 c) {
  return __builtin_amdgcn_mfma_f32_16x16x32_bf16(a, b, c, 0, 0, 0);
}
__device__ __forceinline__ void gload16(const void* g, void* l) {
  __builtin_amdgcn_global_load_lds(
      (const __attribute__((address_space(1))) unsigned int*)g,
      (__attribute__((address_space(3))) unsigned int*)l, 16, 0, 0);
}
__device__ __forceinline__ float tanhfast(float z) {
  float e = __expf(2.0f * z);
  return 1.0f - 2.0f / (e + 1.0f);
}
// L1-bypassing L2 read (flag poll fast path). waitcnt fused in asm (rule #18).
__device__ __forceinline__ int load_sc0_int(const int* p) {
  int v;
  asm volatile("global_load_dword %0, %1, off sc0\n\ts_waitcnt vmcnt(0)"
               : "=&v"(v) : "v"(p) : "memory");
  return v;
}
// L1-bypassing store straight to L2 (flag publish fast path).
__device__ __forceinline__ void store_sc0_int(int* p, int v) {
  asm volatile("global_store_dword %0, %1, off sc0" :: "v"(p), "v"(v) : "memory");
}

// ---------------- prep kernels ----------------
__global__ void k_convert(const float* __restrict__ src, ushort_t* __restrict__ dst, int n) {
  int i = blockIdx.x * blockDim.x + threadIdx.x;
  if (i < n) dst[i] = f2bf(src[i]);
}
__global__ void k_split(const float* __restrict__ src, ushort_t* __restrict__ hi,
                        ushort_t* __restrict__ lo, int n) {
  int i = blockIdx.x * blockDim.x + threadIdx.x;
  if (i < n) {
    float v = src[i];
    ushort_t h = f2bf(v);
    hi[i] = h;
    lo[i] = f2bf(v - bf2f(h));
  }
}
__global__ void k_split_wc(const float* __restrict__ Wc,
                           ushort_t* __restrict__ WiH, ushort_t* __restrict__ WiL,
                           ushort_t* __restrict__ WhH, ushort_t* __restrict__ WhL) {
  int i = blockIdx.x * blockDim.x + threadIdx.x;
  if (i < HDIM * HDIM) {
    int row = i >> 10, k = i & 1023;
    float vi = Wc[(size_t)row * (2 * HDIM) + k];
    float vh = Wc[(size_t)row * (2 * HDIM) + HDIM + k];
    ushort_t ih = f2bf(vi);
    WiH[i] = ih; WiL[i] = f2bf(vi - bf2f(ih));
    ushort_t hh = f2bf(vh);
    WhH[i] = hh; WhL[i] = f2bf(vh - bf2f(hh));
  }
}

// ---------------- generic NT GEMM (validated r1-r10) ----------------
template<int SPLITB, int RELU, int OUTBF>
__global__ __launch_bounds__(256) void gemm_nt(
    const ushort_t* __restrict__ A, const ushort_t* __restrict__ Bhi,
    const ushort_t* __restrict__ Blo, const float* __restrict__ bias,
    float* __restrict__ Cf, ushort_t* __restrict__ Cb,
    int M, int N, int K)
{
  __shared__ ushort_t As[128 * 32];
  __shared__ ushort_t Bh[128 * 32];
  __shared__ ushort_t Bl[128 * 32];
  const int tid = threadIdx.x;
  const int w = tid >> 6, l = tid & 63;
  const int m0 = blockIdx.x * 128, n0 = blockIdx.y * 128;
  const int wr = w >> 1, wc = w & 1;
  const int lr = l & 15, lk = l >> 4;

  f32x4 acc[4][4] = {};
  const int nK = K >> 5;
  const size_t rowB = (size_t)K * 2;

  for (int kk = 0; kk < nK; ++kk) {
    const size_t kbyte = (size_t)kk * 64;
#pragma unroll
    for (int j = 0; j < 2; ++j) {
      int c = (w * 2 + j) * 64 + l;
      int row = c >> 2;
      int kb = (c & 3) * 16;
      gload16((const char*)A + (size_t)(m0 + row) * rowB + kbyte + kb,
              (char*)As + (w * 2 + j) * 1024);
      gload16((const char*)Bhi + (size_t)(n0 + row) * rowB + kbyte + kb,
              (char*)Bh + (w * 2 + j) * 1024);
      if (SPLITB)
        gload16((const char*)Blo + (size_t)(n0 + row) * rowB + kbyte + kb,
                (char*)Bl + (w * 2 + j) * 1024);
    }
    __syncthreads();
    bf16x8 af[4], bhf[4], blf[4];
#pragma unroll
    for (int i = 0; i < 4; ++i) {
      af[i]  = *(const bf16x8*)&As[(wr * 64 + i * 16 + lr) * 32 + lk * 8];
      bhf[i] = *(const bf16x8*)&Bh[(wc * 64 + i * 16 + lr) * 32 + lk * 8];
      if (SPLITB)
        blf[i] = *(const bf16x8*)&Bl[(wc * 64 + i * 16 + lr) * 32 + lk * 8];
    }
#pragma unroll
    for (int i = 0; i < 4; ++i)
#pragma unroll
      for (int j2 = 0; j2 < 4; ++j2) {
        acc[i][j2] = mfma16(af[i], bhf[j2], acc[i][j2]);
        if (SPLITB) acc[i][j2] = mfma16(af[i], blf[j2], acc[i][j2]);
      }
    __syncthreads();
  }
#pragma unroll
  for (int j2 = 0; j2 < 4; ++j2) {
    int n = n0 + wc * 64 + j2 * 16 + lr;
    float bv = bias ? bias[n] : 0.0f;
#pragma unroll
    for (int i = 0; i < 4; ++i) {
#pragma unroll
      for (int r = 0; r < 4; ++r) {
        int m = m0 + wr * 64 + i * 16 + lk * 4 + r;
        float v = acc[i][j2][r] + bv;
        if (RELU) v = fmaxf(v, 0.0f);
        if (OUTBF) Cb[(size_t)m * N + n] = f2bf(v);
        else       Cf[(size_t)m * N + n] = v;
      }
    }
  }
}

// ---------------- persistent scan kernel: r8 skeleton + split A/B flags ------
// 512 blocks x 512 threads (8 waves). Workers: XCDs 0-3 x 32 slots (claim via
// XCC_ID + atomic; over-provisioned grid -> hang-proof). Block (g,c): batch
// rows 16g..16g+15, cols 32c..32c+31, K-slice 128/wave.
// r11 changes vs r8 (1147us): (1) separate A/B flags -- consumer needs h0(i)
// fresh (A=i+1) but h1(i-1) one phase stale (B=i, near-free) -> phase-B
// epilogue off the h0 critical chain; (2) poller wave (w4) polls BETWEEN B1
// and B2, overlapped with the epilogue waves' work; B3 dropped (2 barriers);
// (3) per-phase publish via own-wave vmcnt ack + LDS counter (no cross-phase
// wait, no tid0 bottleneck); (4) P0 prefetch off-chain; flags 64B apart;
// poll throttled (sleep after 4 misses, MALL fallback every 16th);
// setprio(1) around epilogue. Data placement = r8 (LDS WhH, reg WhL/WiH).
// Iter i: A: h0(i)   = h0(i-1) + a0*tanh(P0[i] + Wh*h0(i-1))         [i<SEQ]
//         B: h1(i-1) = h1(i-2) + a1*tanh(WiH*h0(i-1)+Wh*h1(i-2)+b_c) [i>=1]
__global__ __attribute__((amdgpu_waves_per_eu(2, 2))) __launch_bounds__(512)
void scan_kernel(
    const float* __restrict__ P0,
    const ushort_t* __restrict__ WiH, const ushort_t* __restrict__ WiL,
    const ushort_t* __restrict__ WhH, const ushort_t* __restrict__ WhL,
    const float* __restrict__ b_c, const float* __restrict__ taus,
    ushort_t* __restrict__ h0buf,   // SEQ x 64x1024 bf16 (archive)
    ushort_t* __restrict__ H1buf,   // SEQ x 64x1024 bf16 (archive = h1 state)
    float* __restrict__ outHidden, int* __restrict__ sync)
{
  __shared__ float red[4 * 8 * 320];        // [tile(ph,ct)][wave][col*20+row] 40KB
  __shared__ ushort_t WhLds[32 * WPAD];     // WhH slice, padded rows, ~66KB
  __shared__ int meta[2];
  __shared__ int acnt, bcnt;                // per-phase epilogue-done counters

  const int tid = threadIdx.x;
  const int w = tid >> 6, l = tid & 63;
  const int lr = l & 15, lk = l >> 4;

  int* cnt    = sync;                  // [8] per-XCD slot counters
  int* A_l2   = sync + 256;            // [4*32] x 16-int spacing (64B apart)
  int* A_mall = sync + 256 + 4096;
  int* B_l2   = sync + 256 + 8192;
  int* B_mall = sync + 256 + 12288;

  // ---- placement discovery ----
  if (tid == 0) {
    int xcd;
    asm volatile("s_getreg_b32 %0, hwreg(HW_REG_XCC_ID)" : "=s"(xcd));
    int slot = 999;
    if (xcd < 4)
      slot = __hip_atomic_fetch_add(&cnt[xcd], 1, __ATOMIC_RELAXED,
                                    __HIP_MEMORY_SCOPE_AGENT);
    meta[0] = (xcd < 4) ? xcd : -1;
    meta[1] = slot;
    acnt = 0; bcnt = 0;
  }
  __syncthreads();
  const int g = meta[0];
  const int c = meta[1];
  if (g < 0 || c >= 32) return;   // surplus block: exit, frees the CU

  const int rowg = g * 16, colg = c * 32;
  const int kb = w * 128;         // K-slice 128 per wave

  // ---- one-time: WhH slice -> LDS (reg-staged, padded rows) ----
  {
    const ushort_t* wsrc = WhH + (size_t)colg * HDIM;
#pragma unroll
    for (int j = 0; j < 8; ++j) {
      int e = (j * 512 + tid) * 8;
      bf16x8 v = *(const bf16x8*)&wsrc[e];
      *(bf16x8*)&WhLds[(e >> 10) * WPAD + (e & 1023)] = v;
    }
  }
  // ---- one-time: WhL + WiH slices -> registers (64 VGPR, pinned per-iter) ----
  bf16x8 wl[2][4], wi[2][4];
#pragma unroll
  for (int ct = 0; ct < 2; ++ct)
#pragma unroll
    for (int kk = 0; kk < 4; ++kk) {
      size_t off = (size_t)(colg + ct * 16 + lr) * HDIM + kb + kk * 32 + lk * 8;
      wl[ct][kk] = *(const bf16x8*)&WhL[off];
      wi[ct][kk] = *(const bf16x8*)&WiH[off];
    }
  __syncthreads();

  // poller pointers (wave 4): lanes 0-31 -> A flags, lanes 32-63 -> B flags
  const int pl = l & 31;
  const int* fl2p = (l < 32) ? &A_l2[(g * 32 + pl) * 16] : &B_l2[(g * 32 + pl) * 16];
  int*       fmlp = (l < 32) ? &A_mall[(g * 32 + pl) * 16] : &B_mall[(g * 32 + pl) * 16];

  // epilogue mapping (waves 0-3): tile = w = ph*2+ct; lane owns col ec, rows R0..R0+3
  const int ep = (w < 4);
  const int ph = w >> 1, ect = w & 1;
  const int ec = lr, R0 = lk * 4;
  float hm[4] = {0, 0, 0, 0};
  float bcn = 0.f, alpha = 0.f;
  float p0r[4] = {0, 0, 0, 0};
  if (ep) {
    alpha = 0.05f / (taus[ph] + 0.001f);
    bcn = b_c[colg + ect * 16 + ec];
    if (ph == 0) {
#pragma unroll
      for (int j = 0; j < 4; ++j)
        p0r[j] = P0[((size_t)0 * BATCH + rowg + R0 + j) * HDIM + colg + ect * 16 + ec];
    }
  }

  for (int i = 0; i <= SEQ; ++i) {
    // pin register weights live across the backedge
#pragma unroll
    for (int ct = 0; ct < 2; ++ct)
#pragma unroll
      for (int kk = 0; kk < 4; ++kk)
        asm volatile("" : "+v"(wl[ct][kk]), "+v"(wi[ct][kk]));

    bf16x8 f[4] = {}, hh[4] = {};
    f32x4 aA[2] = {}, aI[2] = {}, aH[2] = {};
    if (i >= 1) {
      const ushort_t* h0r = h0buf + (size_t)(i - 1) * BH;   // first touch
#pragma unroll
      for (int kk = 0; kk < 4; ++kk)
        f[kk] = *(const bf16x8*)&h0r[(size_t)(rowg + lr) * HDIM + kb + kk * 32 + lk * 8];
      if (i >= 2) {
        const ushort_t* h1r = H1buf + (size_t)(i - 2) * BH; // first touch
#pragma unroll
        for (int kk = 0; kk < 4; ++kk)
          hh[kk] = *(const bf16x8*)&h1r[(size_t)(rowg + lr) * HDIM + kb + kk * 32 + lk * 8];
      }
#pragma unroll
      for (int ct = 0; ct < 2; ++ct)
#pragma unroll
        for (int kk = 0; kk < 4; ++kk) {
          bf16x8 wh = *(const bf16x8*)&WhLds[(ct * 16 + lr) * WPAD + kb + kk * 32 + lk * 8];
          aA[ct] = mfma16(f[kk], wh, aA[ct]);
          aA[ct] = mfma16(f[kk], wl[ct][kk], aA[ct]);
          aI[ct] = mfma16(f[kk], wi[ct][kk], aI[ct]);
          if (i >= 2) {
            aH[ct] = mfma16(hh[kk], wh, aH[ct]);
            aH[ct] = mfma16(hh[kk], wl[ct][kk], aH[ct]);
          }
        }
    }
    // write partials: D-layout col=l&15, row=lk*4+r -> red[col*20+row] (b128)
    const int wbase = lr * 20 + lk * 4;
#pragma unroll
    for (int ct = 0; ct < 2; ++ct) {
      *(f32x4*)&red[((0 + ct) * 8 + w) * 320 + wbase] = aA[ct];
      f32x4 pb = aI[ct] + aH[ct];
      *(f32x4*)&red[((2 + ct) * 8 + w) * 320 + wbase] = pb;
    }
    __syncthreads();                                   // B1

    if (ep) {
      const bool act = (ph == 0) ? (i < SEQ) : (i >= 1);
      if (act) {
        __builtin_amdgcn_s_setprio(1);
        f32x4 s = {};
        const float* rb = &red[(w * 8) * 320 + ec * 20 + R0];
#pragma unroll
        for (int q = 0; q < 8; ++q)
          s += *(const f32x4*)&rb[q * 320];
        if (ph == 0) {
          ushort_t* dst = &h0buf[(size_t)i * BH + (size_t)(rowg + R0) * HDIM +
                                 colg + ect * 16 + ec];
#pragma unroll
          for (int j = 0; j < 4; ++j) {
            hm[j] += alpha * tanhfast(p0r[j] + s[j]);
            dst[(size_t)j * HDIM] = f2bf(hm[j]);
          }
        } else {
          ushort_t* dst = &H1buf[(size_t)(i - 1) * BH + (size_t)(rowg + R0) * HDIM +
                                 colg + ect * 16 + ec];
#pragma unroll
          for (int j = 0; j < 4; ++j) {
            hm[j] += alpha * tanhfast(s[j] + bcn);
            dst[(size_t)j * HDIM] = f2bf(hm[j]);
          }
        }
        asm volatile("s_waitcnt vmcnt(0)" ::: "memory"); // own stores acked at L2
        if (l == 0) {
          if (ph == 0) {
            int old = __hip_atomic_fetch_add(&acnt, 1, __ATOMIC_ACQ_REL,
                                             __HIP_MEMORY_SCOPE_WORKGROUP);
            if (old == 2 * i + 1) {                      // both A-waves done
              store_sc0_int(&A_l2[(g * 32 + c) * 16], i + 1);
              __hip_atomic_store(&A_mall[(g * 32 + c) * 16], i + 1,
                                 __ATOMIC_RELAXED, __HIP_MEMORY_SCOPE_AGENT);
            }
          } else {
            int old = __hip_atomic_fetch_add(&bcnt, 1, __ATOMIC_ACQ_REL,
                                             __HIP_MEMORY_SCOPE_WORKGROUP);
            if (old == 2 * (i - 1) + 1) {                // both B-waves done
              store_sc0_int(&B_l2[(g * 32 + c) * 16], i);
              __hip_atomic_store(&B_mall[(g * 32 + c) * 16], i,
                                 __ATOMIC_RELAXED, __HIP_MEMORY_SCOPE_AGENT);
            }
          }
        }
        __builtin_amdgcn_s_setprio(0);
      }
      if (ph == 0 && i + 1 < SEQ) {    // prefetch next P0 tile (off-chain)
#pragma unroll
        for (int j = 0; j < 4; ++j)
          p0r[j] = P0[((size_t)(i + 1) * BATCH + rowg + R0 + j) * HDIM +
                      colg + ect * 16 + ec];
      }
    } else if (w == 4 && i < SEQ) {
      // poller: overlapped with epilogue. Need A >= i+1 (fresh), B >= i (stale).
      const int tgt = (l < 32) ? (i + 1) : i;
      for (int r = 0;; ++r) {
        int v = ((r & 15) == 15)
          ? __hip_atomic_load(fmlp, __ATOMIC_RELAXED, __HIP_MEMORY_SCOPE_AGENT)
          : load_sc0_int(fl2p);
        if (__all(v >= tgt)) break;
        if (r >= 4) __builtin_amdgcn_s_sleep(1);
      }
    }
    __syncthreads();                                   // B2 (epilogue+poll done)
  }

  // hidden_final [2][64][1024]: layer = ph
  if (ep) {
    float* dst = &outHidden[(size_t)ph * BH + (size_t)(rowg + R0) * HDIM +
                            colg + ect * 16 + ec];
#pragma unroll
    for (int j = 0; j < 4; ++j) dst[(size_t)j * HDIM] = hm[j];
  }
}

// ---------------- host ----------------
extern "C" void kernel_launch(void* const* d_in, const int* in_sizes, int n_in,
                              void* d_out, int out_size, void* d_ws, size_t ws_size,
                              hipStream_t stream) {
  const float* x    = (const float*)d_in[0];
  const float* W_in = (const float*)d_in[1];
  const float* b_in = (const float*)d_in[2];
  const float* W_c  = (const float*)d_in[3];
  const float* b_c  = (const float*)d_in[4];
  const float* taus = (const float*)d_in[5];
  const float* W_o1 = (const float*)d_in[6];
  const float* b_o1 = (const float*)d_in[7];
  const float* W_o2 = (const float*)d_in[8];
  const float* b_o2 = (const float*)d_in[9];
  float* out = (float*)d_out;

  char* ws = (char*)d_ws;
  size_t off = 0;
  auto alloc = [&](size_t bytes) -> char* {
    char* p = ws + off;
    off += (bytes + 255) & ~(size_t)255;
    return p;
  };
  ushort_t* x_bf  = (ushort_t*)alloc((size_t)MTOT * INDIM * 2);     // 16 MB
  ushort_t* xp_b  = (ushort_t*)alloc((size_t)MTOT * HDIM * 2);      // 32 MB
  float*    P0    = (float*)   alloc((size_t)MTOT * HDIM * 4);      // 64 MB
  ushort_t* H1buf = (ushort_t*)alloc((size_t)MTOT * HDIM * 2);      // 32 MB
  ushort_t* h0buf = (ushort_t*)alloc((size_t)SEQ * BH * 2);         // 32 MB
  ushort_t* O1    = (ushort_t*)alloc((size_t)MTOT * (HDIM/2) * 2);  // 16 MB
  ushort_t* WiH   = (ushort_t*)alloc((size_t)HDIM * HDIM * 2);
  ushort_t* WiL   = (ushort_t*)alloc((size_t)HDIM * HDIM * 2);
  ushort_t* WhH   = (ushort_t*)alloc((size_t)HDIM * HDIM * 2);
  ushort_t* WhL   = (ushort_t*)alloc((size_t)HDIM * HDIM * 2);
  ushort_t* WinH  = (ushort_t*)alloc((size_t)HDIM * INDIM * 2);
  ushort_t* WinL  = (ushort_t*)alloc((size_t)HDIM * INDIM * 2);
  ushort_t* Wo1b  = (ushort_t*)alloc((size_t)(HDIM/2) * HDIM * 2);
  ushort_t* Wo2b  = (ushort_t*)alloc((size_t)OUTDIM * (HDIM/2) * 2);
  int*      sync  = (int*)     alloc(65536);
  if (off > ws_size) return;

  hipMemsetAsync(sync, 0, 65536, stream);

  k_convert<<<(MTOT * INDIM + 255) / 256, 256, 0, stream>>>(x, x_bf, MTOT * INDIM);
  k_split<<<(HDIM * INDIM + 255) / 256, 256, 0, stream>>>(W_in, WinH, WinL, HDIM * INDIM);
  k_split_wc<<<(HDIM * HDIM + 255) / 256, 256, 0, stream>>>(W_c, WiH, WiL, WhH, WhL);
  k_convert<<<((HDIM/2) * HDIM + 255) / 256, 256, 0, stream>>>(W_o1, Wo1b, (HDIM/2) * HDIM);
  k_convert<<<(OUTDIM * (HDIM/2) + 255) / 256, 256, 0, stream>>>(W_o2, Wo2b, OUTDIM * (HDIM/2));

  // xp = x @ W_in^T + b_in   -> bf16
  gemm_nt<1, 0, 1><<<dim3(MTOT / 128, HDIM / 128), 256, 0, stream>>>(
      x_bf, WinH, WinL, b_in, nullptr, xp_b, MTOT, HDIM, INDIM);
  // P0 = xp @ Wi^T + b_c     -> fp32
  gemm_nt<1, 0, 0><<<dim3(MTOT / 128, HDIM / 128), 256, 0, stream>>>(
      xp_b, WiH, WiL, b_c, P0, nullptr, MTOT, HDIM, HDIM);

  // sequential scan: 4 XCD-local groups x 32 worker blocks x 8 waves
  scan_kernel<<<512, 512, 0, stream>>>(P0, WiH, WiL, WhH, WhL, b_c, taus,
                                       h0buf, H1buf,
                                       out + (size_t)SEQ * BATCH * OUTDIM, sync);

  // O1 = relu(H1 @ W_o1^T + b_o1) -> bf16
  gemm_nt<0, 1, 1><<<dim3(MTOT / 128, (HDIM/2) / 128), 256, 0, stream>>>(
      H1buf, Wo1b, nullptr, b_o1, nullptr, O1, MTOT, HDIM / 2, HDIM);
  // out = O1 @ W_o2^T + b_o2 -> fp32
  gemm_nt<0, 0, 0><<<dim3(MTOT / 128, OUTDIM / 128), 256, 0, stream>>>(
      O1, Wo2b, nullptr, b_o2, out, nullptr, MTOT, OUTDIM, HDIM / 2);
}